// Round 11
// baseline (775.282 us; speedup 1.0000x reference)
//
#include <hip/hip_runtime.h>
#include <math.h>

#define N_NODES 50000
#define N_EDGES 800000
#define HID 64
#define N_GRAPHS 256
#define BN_EPS 1e-5f
#define GATE_EPS 1e-6f

static inline size_t align256(size_t x) { return (x + 255) & ~(size_t)255; }

// ---------------------------------------------------------------- utilities

__global__ void k_zero(int* __restrict__ p, int n) {
    for (int i = blockIdx.x * blockDim.x + threadIdx.x; i < n; i += gridDim.x * blockDim.x)
        p[i] = 0;
}

__global__ void k_deg(const int* __restrict__ dst, int* __restrict__ deg) {
    for (int i = blockIdx.x * blockDim.x + threadIdx.x; i < N_EDGES; i += gridDim.x * blockDim.x)
        atomicAdd(&deg[dst[i]], 1);
}

__global__ void k_norm(const int* __restrict__ deg, float* __restrict__ norm) {
    int i = blockIdx.x * blockDim.x + threadIdx.x;
    if (i < N_NODES) norm[i] = 1.0f / sqrtf(fmaxf((float)deg[i], 1.0f));
}

// exclusive scan of deg -> start (256/block, 2-level)
__global__ void k_scan1(const int* __restrict__ deg, int* __restrict__ start,
                        int* __restrict__ blksum) {
    __shared__ int s[256];
    int t = threadIdx.x;
    int i = blockIdx.x * 256 + t;
    int v = (i < N_NODES) ? deg[i] : 0;
    s[t] = v;
    __syncthreads();
    for (int off = 1; off < 256; off <<= 1) {
        int x = (t >= off) ? s[t - off] : 0;
        __syncthreads();
        s[t] += x;
        __syncthreads();
    }
    if (i < N_NODES) start[i] = s[t] - v;   // exclusive
    if (t == 255) blksum[blockIdx.x] = s[255];
}

__global__ void k_scan2(int* __restrict__ blksum, int nb) {
    __shared__ int s[256];
    int t = threadIdx.x;
    int v = (t < nb) ? blksum[t] : 0;
    s[t] = v;
    __syncthreads();
    for (int off = 1; off < 256; off <<= 1) {
        int x = (t >= off) ? s[t - off] : 0;
        __syncthreads();
        s[t] += x;
        __syncthreads();
    }
    if (t < nb) blksum[t] = s[t] - v;       // exclusive block offsets
}

__global__ void k_scan3(int* __restrict__ start, const int* __restrict__ blksum,
                        int* __restrict__ cursor) {
    int i = blockIdx.x * 256 + threadIdx.x;
    if (i < N_NODES) {
        int v = start[i] + blksum[blockIdx.x];
        start[i] = v;
        cursor[i] = v;
    }
    if (blockIdx.x == 0 && threadIdx.x == 0) start[N_NODES] = N_EDGES;
}

// scatter edges into dst-sorted order; meta = {src|etype<<24, norm[src] bits}
__global__ void k_scatter(const int* __restrict__ dst, const int* __restrict__ src,
                          const int* __restrict__ etype, const float* __restrict__ norm,
                          int* __restrict__ cursor, int2* __restrict__ edge_meta) {
    for (int i = blockIdx.x * blockDim.x + threadIdx.x; i < N_EDGES; i += gridDim.x * blockDim.x) {
        int p = atomicAdd(&cursor[dst[i]], 1);
        int s = src[i];
        edge_meta[p] = make_int2(s | (etype[i] << 24), __float_as_int(norm[s]));
    }
}

// node encoder into pair layout: pair[n][c] = {emb, 0}
__global__ __launch_bounds__(256) void k_embed(const int* __restrict__ h,
                                               const float* __restrict__ node_emb,
                                               float4* __restrict__ pair4) {
    const int total2 = N_NODES * (HID / 2);     // one float4 covers 2 pair entries
    for (int i = blockIdx.x * blockDim.x + threadIdx.x; i < total2; i += gridDim.x * blockDim.x) {
        int n = i >> 5, c2 = i & 31;
        float2 e = ((const float2*)node_emb)[h[n] * (HID / 2) + c2];
        pair4[i] = make_float4(e.x, 0.f, e.y, 0.f);
    }
}

// ------------------------------------------------------- fused edge kernel
// One wave per 4 NODES (lane == channel), 4 independent edge streams,
// explicit 2-stage software pipeline hard-fenced with sched_barrier(0):
//   {issue 4 pair-gathers for it+1; issue meta/ef prefetch for it+2}
//   -> sched_barrier(0) -> {consume it entirely from registers}.
// r6/r8 post-mortem: without the fence the scheduler sinks each load to its
// use (VGPR 24-28, ~1 outstanding gather/wave, HBM stuck at 43%). The fence
// forces the load batch live across the barrier.
// hf_new/hf_old are interleaved as float2 pairs: ONE dwordx2 gather per edge.
// r9 post-mortem: pairA+pairB overflowed ws_size (~276MB > limit) -> GPU
// fault. Fixed: single pair buffer, k_hupd updates it in place (elementwise).
//
// MODE 0: ef_prev = emb table; no BN-apply; no ef write.
// MODE 1: ef_prev = emb table; apply BN_e(0); first ef write.
// MODE 2: ef_prev = global ef;  apply BN_e(prev); ef write.
// MODE 3: ef_prev = global ef;  apply BN_e(prev); NO write, no e-stats.
template <int MODE>
__global__ __launch_bounds__(256, 4) void k_edge(
    const int* __restrict__ start, const int2* __restrict__ edge_meta,
    const float* __restrict__ edge_emb,
    float* __restrict__ ef,
    const float2* __restrict__ pair,     // {hf_new, hf_old} per node-channel
    const float* __restrict__ norm, float* __restrict__ h_new,
    const float* __restrict__ stats_prev, const float* __restrict__ gamma_prev,
    const float* __restrict__ beta_prev,
    float* __restrict__ stats_e_out, float* __restrict__ stats_h_out) {
    const int lane = threadIdx.x & 63;
    const int wid = __builtin_amdgcn_readfirstlane(blockIdx.x * 4 + (threadIdx.x >> 6));
    const int n0 = wid * 4;   // this wave's 4 consecutive nodes

    __shared__ float s_emb[4 * HID];
    if (MODE <= 1) {
        for (int i = threadIdx.x; i < 4 * HID; i += blockDim.x) s_emb[i] = edge_emb[i];
        __syncthreads();
    }
    float a_prev = 0.f, c_prev = 0.f;
    if (MODE >= 1) {
        float s1 = stats_prev[lane], s2 = stats_prev[HID + lane];
        float mu = s1 * (1.0f / N_EDGES);
        float var = s2 * (1.0f / N_EDGES) - mu * mu;
        float rstd = 1.0f / sqrtf(var + BN_EPS);
        a_prev = gamma_prev[lane] * rstd;
        c_prev = beta_prev[lane] - mu * a_prev;
    }

    int jbeg[4], len[4];
    float hnn[4], hon[4], amsg[4], aden[4];
    int maxlen = 0;
#pragma unroll
    for (int k = 0; k < 4; ++k) {
        jbeg[k] = __builtin_amdgcn_readfirstlane(start[n0 + k]);
        len[k] = __builtin_amdgcn_readfirstlane(start[n0 + k + 1]) - jbeg[k];
        maxlen = max(maxlen, len[k]);
        float2 o = pair[(size_t)(n0 + k) * HID + lane];
        hnn[k] = o.x;
        hon[k] = (MODE >= 1) ? o.y : 0.f;
        amsg[k] = 0.f;
        aden[k] = 0.f;
    }

    // clamped slot index for stream k at iteration it (always in-bounds;
    // clamped reads are dead — act=false suppresses their consumption)
    auto eslot = [&](int k, int it) {
        int itc = min(it, max(len[k] - 1, 0));
        return min(jbeg[k] + itc, N_EDGES - 1);
    };

    float sum_e = 0.f, sumsq_e = 0.f, sum_h = 0.f, sumsq_h = 0.f;
    if (maxlen > 0) {
        int2 mt0[4], mt1[4];
        float ef0[4], ef1[4];
        float2 hp0[4];
        // ---- prologue: slot-0 meta/ef, slot-0 gathers, slot-1 meta/ef
#pragma unroll
        for (int k = 0; k < 4; ++k) {
            const int j = eslot(k, 0);
            mt0[k] = edge_meta[j];
            ef0[k] = (MODE >= 2) ? ef[(size_t)j * HID + lane] : 0.f;
        }
#pragma unroll
        for (int k = 0; k < 4; ++k)
            hp0[k] = pair[(size_t)(mt0[k].x & 0xFFFFFF) * HID + lane];
#pragma unroll
        for (int k = 0; k < 4; ++k) {
            const int j = eslot(k, 1);
            mt1[k] = edge_meta[j];
            ef1[k] = (MODE >= 2) ? ef[(size_t)j * HID + lane] : 0.f;
        }
        for (int it = 0; it < maxlen; ++it) {
            // ---- stage A: gathers for it+1 (mt1 already resident)
            float2 hp1[4];
#pragma unroll
            for (int k = 0; k < 4; ++k)
                hp1[k] = pair[(size_t)(mt1[k].x & 0xFFFFFF) * HID + lane];
            // ---- stage B: meta/ef prefetch for it+2
            int2 mt2[4];
            float ef2[4];
            const int itn = (it + 2 < maxlen) ? it + 2 : maxlen - 1;
#pragma unroll
            for (int k = 0; k < 4; ++k) {
                const int j = eslot(k, itn);
                mt2[k] = edge_meta[j];
                ef2[k] = (MODE >= 2) ? ef[(size_t)j * HID + lane] : 0.f;
            }
            // ---- fence: nothing crosses; the load batch stays in flight
            __builtin_amdgcn_sched_barrier(0);
            // ---- consume iteration it (all operands in registers)
#pragma unroll
            for (int k = 0; k < 4; ++k) {
                const bool act = it < len[k];                  // wave-uniform
                float efv;
                if (MODE == 0) {
                    efv = s_emb[(mt0[k].x >> 24) * HID + lane];
                } else if (MODE == 1) {
                    const float e0v = s_emb[(mt0[k].x >> 24) * HID + lane];
                    const float ep = hp0[k].y + hon[k] + e0v;
                    efv = e0v + fmaxf(a_prev * ep + c_prev, 0.f);
                    if (act) ef[(size_t)(jbeg[k] + it) * HID + lane] = efv;
                } else {
                    const float ep = hp0[k].y + hon[k] + ef0[k];
                    efv = ef0[k] + fmaxf(a_prev * ep + c_prev, 0.f);
                    if (MODE == 2) {
                        if (act) ef[(size_t)(jbeg[k] + it) * HID + lane] = efv;
                    }
                }
                const float en = hp0[k].x + hnn[k] + efv;
                const float sgm = 1.0f / (1.0f + __expf(-en));
                if (act) {
                    amsg[k] += sgm * hp0[k].x * __int_as_float(mt0[k].y);
                    aden[k] += sgm;
                    if (MODE != 3) { sum_e += en; sumsq_e += en * en; }
                }
            }
            // ---- rotate pipeline
#pragma unroll
            for (int k = 0; k < 4; ++k) {
                mt0[k] = mt1[k]; ef0[k] = ef1[k]; hp0[k] = hp1[k];
                mt1[k] = mt2[k]; ef1[k] = ef2[k];
            }
        }
    }

#pragma unroll
    for (int k = 0; k < 4; ++k) {
        const float nm = norm[n0 + k];
        const float hval = (hnn[k] * nm + amsg[k] / (aden[k] + GATE_EPS)) * nm;
        h_new[(n0 + k) * HID + lane] = hval;
        sum_h += hval;
        sumsq_h += hval * hval;
    }

    __shared__ float sred[4][256];
    sred[0][threadIdx.x] = sum_e;
    sred[1][threadIdx.x] = sumsq_e;
    sred[2][threadIdx.x] = sum_h;
    sred[3][threadIdx.x] = sumsq_h;
    __syncthreads();
    if (threadIdx.x < 64) {
        const int t = threadIdx.x;
        if (MODE != 3) {
            float t1 = sred[0][t] + sred[0][t + 64] + sred[0][t + 128] + sred[0][t + 192];
            float t2 = sred[1][t] + sred[1][t + 64] + sred[1][t + 128] + sred[1][t + 192];
            atomicAdd(&stats_e_out[t], t1);
            atomicAdd(&stats_e_out[HID + t], t2);
        }
        float t3 = sred[2][t] + sred[2][t + 64] + sred[2][t + 128] + sred[2][t + 192];
        float t4 = sred[3][t] + sred[3][t + 64] + sred[3][t + 128] + sred[3][t + 192];
        atomicAdd(&stats_h_out[t], t3);
        atomicAdd(&stats_h_out[HID + t], t4);
    }
}

// ------------------------------------------------------------- node update
// IN-PLACE: pair[i] = {pair[i].x + relu(bn_h(h_new[i])), pair[i].x}
// Elementwise read-modify-write of the same float4 -> single buffer is safe.
__global__ __launch_bounds__(256) void k_hupd(
    float4* pair4, const float2* __restrict__ h_new2,
    const float* __restrict__ stats, const float* __restrict__ gamma,
    const float* __restrict__ beta) {
    const int tid = blockIdx.x * blockDim.x + threadIdx.x;
    const int cb = (tid & 31) * 2;    // this thread's channel pair
    float a[2], c[2];
#pragma unroll
    for (int k = 0; k < 2; ++k) {
        int ch = cb + k;
        float mu = stats[ch] * (1.0f / N_NODES);
        float var = stats[HID + ch] * (1.0f / N_NODES) - mu * mu;
        float rstd = 1.0f / sqrtf(var + BN_EPS);
        a[k] = gamma[ch] * rstd;
        c[k] = beta[ch] - mu * a[k];
    }
    const int total2 = N_NODES * (HID / 2);
    for (int i = tid; i < total2; i += gridDim.x * blockDim.x) {
        float4 p = pair4[i];              // {new0, old0, new1, old1}
        float2 hn = h_new2[i];
        float o0 = p.x + fmaxf(a[0] * hn.x + c[0], 0.f);
        float o1 = p.z + fmaxf(a[1] * hn.y + c[1], 0.f);
        pair4[i] = make_float4(o0, p.x, o1, p.z);
    }
}

// --------------------------------------------- fused mean-pool + MLP head
// graph_ids is sorted: one block per graph, binary-search the node range.
__global__ __launch_bounds__(256) void k_poolmlp(
    const float2* __restrict__ pair, const int* __restrict__ graph_ids,
    const float* __restrict__ W1, const float* __restrict__ b1,
    const float* __restrict__ W2, const float* __restrict__ b2,
    const float* __restrict__ W3, const float* __restrict__ b3,
    float* __restrict__ out) {
    const int g = blockIdx.x;
    int a = 0, b = N_NODES;
    while (a < b) { int m = (a + b) >> 1; if (graph_ids[m] < g) a = m + 1; else b = m; }
    const int lo = a;
    b = N_NODES;
    while (a < b) { int m = (a + b) >> 1; if (graph_ids[m] < g + 1) a = m + 1; else b = m; }
    const int hi = a;

    const int lane = threadIdx.x & 63, w = threadIdx.x >> 6;
    float acc = 0.f;
    for (int n = lo + w; n < hi; n += 4) acc += pair[(size_t)n * HID + lane].x;
    __shared__ float sred[256];
    __shared__ float sh[64], sx1[32], sx2[16];
    sred[threadIdx.x] = acc;
    __syncthreads();
    if (threadIdx.x < 64) {
        float tot = sred[lane] + sred[lane + 64] + sred[lane + 128] + sred[lane + 192];
        sh[lane] = tot / fmaxf((float)(hi - lo), 1.0f);
    }
    __syncthreads();
    const int t = threadIdx.x;
    if (t < 32) {
        float s = b1[t];
        for (int c = 0; c < 64; ++c) s += sh[c] * W1[c * 32 + t];
        sx1[t] = fmaxf(s, 0.f);
    }
    __syncthreads();
    if (t < 16) {
        float s = b2[t];
        for (int k = 0; k < 32; ++k) s += sx1[k] * W2[k * 16 + t];
        sx2[t] = fmaxf(s, 0.f);
    }
    __syncthreads();
    if (t == 0) {
        float s = b3[0];
        for (int k = 0; k < 16; ++k) s += sx2[k] * W3[k];
        out[g] = s;
    }
}

// -------------------------------------------------------------------- launch

extern "C" void kernel_launch(void* const* d_in, const int* in_sizes, int n_in,
                              void* d_out, int out_size, void* d_ws, size_t ws_size,
                              hipStream_t stream) {
    const int* h_idx      = (const int*)d_in[0];
    const int* e_idx      = (const int*)d_in[1];
    const int* src        = (const int*)d_in[2];
    const int* dst        = (const int*)d_in[3];
    const int* graph_ids  = (const int*)d_in[4];
    const float* node_emb = (const float*)d_in[5];
    const float* edge_emb = (const float*)d_in[6];
    const float* bnh_g    = (const float*)d_in[7];
    const float* bnh_b    = (const float*)d_in[8];
    const float* bne_g    = (const float*)d_in[9];
    const float* bne_b    = (const float*)d_in[10];
    const float* W1       = (const float*)d_in[11];
    const float* b1       = (const float*)d_in[12];
    const float* W2       = (const float*)d_in[13];
    const float* b2       = (const float*)d_in[14];
    const float* W3       = (const float*)d_in[15];
    const float* b3       = (const float*)d_in[16];
    float* out = (float*)d_out;

    // ---- workspace layout (~250.5 MB, within round-8's proven envelope)
    char* w = (char*)d_ws;
    size_t off = 0;
    auto alloc = [&](size_t bytes) -> void* {
        void* p = w + off;
        off = align256(off + bytes);
        return p;
    };
    float*  ef        = (float*)alloc((size_t)N_EDGES * HID * 4);    // sorted-slot order
    float2* pair      = (float2*)alloc((size_t)N_NODES * HID * 8);   // {new, old}, in-place
    float*  h_new     = (float*)alloc((size_t)N_NODES * HID * 4);
    float*  norm      = (float*)alloc((size_t)N_NODES * 4);
    int2*   edge_meta = (int2*)alloc((size_t)N_EDGES * 8);
    int*    start     = (int*)alloc((size_t)(N_NODES + 1) * 4);
    int*    cursor    = (int*)alloc((size_t)N_NODES * 4);
    int*    blksum    = (int*)alloc(256 * 4);
    // zero-initialized region (contiguous)
    size_t zoff = off;
    int*    deg       = (int*)alloc((size_t)N_NODES * 4);
    float*  stats_e   = (float*)alloc(4 * 2 * HID * 4);
    float*  stats_h   = (float*)alloc(4 * 2 * HID * 4);
    int zero_elems = (int)((off - zoff) / 4);
    int* zbase = (int*)(w + zoff);

    const int NB_SCAN = (N_NODES + 255) / 256;   // 196

    // ---- preprocessing
    k_zero<<<64, 256, 0, stream>>>(zbase, zero_elems);
    k_deg<<<1024, 256, 0, stream>>>(dst, deg);
    k_norm<<<NB_SCAN, 256, 0, stream>>>(deg, norm);
    k_scan1<<<NB_SCAN, 256, 0, stream>>>(deg, start, blksum);
    k_scan2<<<1, 256, 0, stream>>>(blksum, NB_SCAN);
    k_scan3<<<NB_SCAN, 256, 0, stream>>>(start, blksum, cursor);
    k_scatter<<<1024, 256, 0, stream>>>(dst, src, e_idx, norm, cursor, edge_meta);
    k_embed<<<512, 256, 0, stream>>>(h_idx, node_emb, (float4*)pair);

    const int EG = N_NODES / 16;   // 3125 blocks: 4 waves x 4 nodes each, exact
    const int NG = 512;            // node-kernel blocks

    // ---- layer 0 (ef_prev from emb table, no BN-apply)
    k_edge<0><<<EG, 256, 0, stream>>>(start, edge_meta, edge_emb, ef,
        pair, norm, h_new, nullptr, nullptr, nullptr,
        stats_e + 0 * 128, stats_h + 0 * 128);
    k_hupd<<<NG, 256, 0, stream>>>((float4*)pair, (const float2*)h_new,
        stats_h + 0 * 128, bnh_g + 0 * HID, bnh_b + 0 * HID);

    // ---- layer 1 (ef_prev from emb table; apply BN_e(0); first ef write)
    k_edge<1><<<EG, 256, 0, stream>>>(start, edge_meta, edge_emb, ef,
        pair, norm, h_new, stats_e + 0 * 128, bne_g + 0 * HID, bne_b + 0 * HID,
        stats_e + 1 * 128, stats_h + 1 * 128);
    k_hupd<<<NG, 256, 0, stream>>>((float4*)pair, (const float2*)h_new,
        stats_h + 1 * 128, bnh_g + 1 * HID, bnh_b + 1 * HID);

    // ---- layer 2 (ef read+write)
    k_edge<2><<<EG, 256, 0, stream>>>(start, edge_meta, edge_emb, ef,
        pair, norm, h_new, stats_e + 1 * 128, bne_g + 1 * HID, bne_b + 1 * HID,
        stats_e + 2 * 128, stats_h + 2 * 128);
    k_hupd<<<NG, 256, 0, stream>>>((float4*)pair, (const float2*)h_new,
        stats_h + 2 * 128, bnh_g + 2 * HID, bnh_b + 2 * HID);

    // ---- layer 3 (ef read only; e-side outputs dead)
    k_edge<3><<<EG, 256, 0, stream>>>(start, edge_meta, edge_emb, ef,
        pair, norm, h_new, stats_e + 2 * 128, bne_g + 2 * HID, bne_b + 2 * HID,
        stats_e + 3 * 128, stats_h + 3 * 128);
    k_hupd<<<NG, 256, 0, stream>>>((float4*)pair, (const float2*)h_new,
        stats_h + 3 * 128, bnh_g + 3 * HID, bnh_b + 3 * HID);

    // ---- fused mean-pool + MLP readout
    k_poolmlp<<<N_GRAPHS, 256, 0, stream>>>(pair, graph_ids, W1, b1, W2, b2, W3, b3, out);
}